// Round 2
// baseline (235.178 us; speedup 1.0000x reference)
//
#include <hip/hip_runtime.h>
#include <math.h>

namespace {
constexpr int B = 4, R = 10, N = 64, E = 64, D = 300, H = 512;
constexpr int BR = B * R;        // 40
constexpr int NE = N * E;        // 4096
constexpr int S = BR * NE;       // 163840 score elements
constexpr float SLOPE = 0.2f;

// ws layout in floats (all float4-aligned where needed)
constexpr int OFF_V1  = 0;                 // 300   Wn @ a1
constexpr int OFF_V2  = OFF_V1 + 300;      // 300   Wn @ a2
constexpr int OFF_U1  = OFF_V2 + 300;      // 512   Wq @ a1
constexpr int OFF_U2  = OFF_U1 + H;        // 512   Wq @ a2
constexpr int OFF_QP  = OFF_U2 + H;        // 40*512 q_proj
constexpr int OFF_QA1 = OFF_QP + BR * H;   // 40    q_proj . a1
constexpr int OFF_QA2 = OFF_QA1 + BR;      // 40    q_proj . a2
constexpr int OFF_S1  = OFF_QA2 + BR;      // 2560  scores1[b,r,n]
constexpr int OFF_SC  = OFF_S1 + BR * N;   // 163840 scores -> attn (in place)
constexpr int OFF_WO  = OFF_SC + S;        // 1310720 w_original
// total: 1,499,304 floats = 5.72 MB
}

__device__ inline float waveReduce(float v) {
#pragma unroll
  for (int o = 32; o > 0; o >>= 1) v += __shfl_xor(v, o, 64);
  return v;
}

// grid 812 x 64: one wave per W row; dots row with a1 and a2.
__global__ void k_vecs(const float* __restrict__ W, const float* __restrict__ a,
                       float* __restrict__ ws) {
  int row = blockIdx.x;      // 0..811 (0..299 -> Wn, 300..811 -> Wq)
  int lane = threadIdx.x;    // 0..63
  const float4* rf  = reinterpret_cast<const float4*>(W + (size_t)row * H);
  const float4* a1f = reinterpret_cast<const float4*>(a);
  const float4* a2f = reinterpret_cast<const float4*>(a + H);
  float4 x0 = rf[lane], x1 = rf[64 + lane];
  float4 p0 = a1f[lane], p1 = a1f[64 + lane];
  float4 q0 = a2f[lane], q1 = a2f[64 + lane];
  float s1 = x0.x * p0.x + x0.y * p0.y + x0.z * p0.z + x0.w * p0.w
           + x1.x * p1.x + x1.y * p1.y + x1.z * p1.z + x1.w * p1.w;
  float s2 = x0.x * q0.x + x0.y * q0.y + x0.z * q0.z + x0.w * q0.w
           + x1.x * q1.x + x1.y * q1.y + x1.z * q1.z + x1.w * q1.w;
  s1 = waveReduce(s1);
  s2 = waveReduce(s2);
  if (lane == 0) {
    if (row < D) { ws[OFF_V1 + row] = s1; ws[OFF_V2 + row] = s2; }
    else         { ws[OFF_U1 + (row - D)] = s1; ws[OFF_U2 + (row - D)] = s2; }
  }
}

// grid 40 x 512: q_proj row per block + qa1/qa2 scalars.
__global__ void k_qproj(const float* __restrict__ ques, const float* __restrict__ W,
                        float* __restrict__ ws) {
  int br = blockIdx.x, h = threadIdx.x;
  __shared__ float qs[H];
  __shared__ float red[16];
  qs[h] = ques[(size_t)br * H + h];
  __syncthreads();
  float acc = 0.f;
#pragma unroll 8
  for (int q = 0; q < H; ++q) acc = fmaf(qs[q], W[(size_t)(D + q) * H + h], acc);
  ws[OFF_QP + br * H + h] = acc;
  float p1 = qs[h] * ws[OFF_U1 + h];
  float p2 = qs[h] * ws[OFF_U2 + h];
  p1 = waveReduce(p1);
  p2 = waveReduce(p2);
  int lane = h & 63, w = h >> 6;
  if (lane == 0) { red[w] = p1; red[8 + w] = p2; }
  __syncthreads();
  if (h == 0) {
    float t1 = 0.f, t2 = 0.f;
#pragma unroll
    for (int i = 0; i < 8; ++i) { t1 += red[i]; t2 += red[8 + i]; }
    ws[OFF_QA1 + br] = t1;
    ws[OFF_QA2 + br] = t2;
  }
}

// grid 40 x 256 (4 waves): scores1[br,n] = orig[br,n,:].v1 + qa1[br]
__global__ void k_scores1(const float* __restrict__ orig, float* __restrict__ ws) {
  int br = blockIdx.x;
  int wave = threadIdx.x >> 6, lane = threadIdx.x & 63;
  const float4* vf = reinterpret_cast<const float4*>(ws + OFF_V1);
  float4 va = vf[lane];
  float4 vb = (lane < 11) ? vf[64 + lane] : make_float4(0.f, 0.f, 0.f, 0.f);
  float qa1 = ws[OFF_QA1 + br];
  for (int n = wave; n < N; n += 4) {
    const float4* rf = reinterpret_cast<const float4*>(orig + ((size_t)br * N + n) * D);
    float4 x = rf[lane];
    float acc = x.x * va.x + x.y * va.y + x.z * va.z + x.w * va.w;
    if (lane < 11) {
      float4 y = rf[64 + lane];
      acc += y.x * vb.x + y.y * vb.y + y.z * vb.z + y.w * vb.w;
    }
    acc = waveReduce(acc);
    if (lane == 0) ws[OFF_S1 + br * N + n] = acc + qa1;
  }
}

// grid 40960 x 256: one wave per (b,r,n,e). The dominant pass: reads adj once.
__global__ void k_scores2(const float* __restrict__ adj, float* __restrict__ ws) {
  int g = blockIdx.x * 4 + (threadIdx.x >> 6);   // 0..S-1
  int lane = threadIdx.x & 63;
  const float4* vf = reinterpret_cast<const float4*>(ws + OFF_V2);
  float4 va = vf[lane];
  float4 vb = (lane < 11) ? vf[64 + lane] : make_float4(0.f, 0.f, 0.f, 0.f);
  const float4* rf = reinterpret_cast<const float4*>(adj + (size_t)g * D);
  float4 x = rf[lane];
  float acc = x.x * va.x + x.y * va.y + x.z * va.z + x.w * va.w;
  if (lane < 11) {
    float4 y = rf[64 + lane];
    acc += y.x * vb.x + y.y * vb.y + y.z * vb.z + y.w * vb.w;
  }
  acc = waveReduce(acc);
  if (lane == 0) {
    int br = g >> 12;   // / (N*E)
    int brn = g >> 6;   // / E
    float sc = acc + ws[OFF_QA2 + br] + ws[OFF_S1 + brn];
    ws[OFF_SC + g] = sc > 0.f ? sc : SLOPE * sc;
  }
}

// grid 64 x 256: softmax over r (stride NE) for each (b,n,e); in place.
__global__ void k_softmax(float* __restrict__ ws) {
  int t = blockIdx.x * 256 + threadIdx.x;  // 0..16383 = B*N*E
  int b = t >> 12;
  int rem = t & 4095;
  float* sc = ws + OFF_SC;
  size_t base = ((size_t)b * R) * NE + rem;
  float v[R];
  float m = -1e30f;
#pragma unroll
  for (int r = 0; r < R; ++r) { v[r] = sc[base + (size_t)r * NE]; m = fmaxf(m, v[r]); }
  float s = 0.f;
#pragma unroll
  for (int r = 0; r < R; ++r) { v[r] = expf(v[r] - m); s += v[r]; }
  float inv = 1.f / s;
#pragma unroll
  for (int r = 0; r < R; ++r) sc[base + (size_t)r * NE] = v[r] * inv;
}

// grid (40, 8) x 256: w_original[br] = orig[br] @ Wn + q_proj[br]  (tiled GEMM, BK=60)
__global__ void k_wo(const float* __restrict__ orig, const float* __restrict__ W,
                     float* __restrict__ ws) {
  int br = blockIdx.x, h0 = blockIdx.y * 64;
  int t = threadIdx.x;
  __shared__ float sA[64 * 60];
  __shared__ float sB[60 * 64];
  int tn = t >> 4, th = t & 15;
  float acc[4][4] = {};
  for (int k0 = 0; k0 < D; k0 += 60) {
    __syncthreads();
    for (int idx = t; idx < 64 * 60; idx += 256) {
      int n = idx / 60, kk = idx % 60;
      sA[idx] = orig[((size_t)br * N + n) * D + k0 + kk];
    }
    for (int idx = t; idx < 60 * 64; idx += 256) {
      int kk = idx >> 6, hh = idx & 63;
      sB[idx] = W[(size_t)(k0 + kk) * H + h0 + hh];
    }
    __syncthreads();
    for (int kk = 0; kk < 60; ++kk) {
      float av[4], bv[4];
#pragma unroll
      for (int i = 0; i < 4; ++i) av[i] = sA[(tn * 4 + i) * 60 + kk];
#pragma unroll
      for (int j = 0; j < 4; ++j) bv[j] = sB[kk * 64 + th * 4 + j];
#pragma unroll
      for (int i = 0; i < 4; ++i)
#pragma unroll
        for (int j = 0; j < 4; ++j) acc[i][j] = fmaf(av[i], bv[j], acc[i][j]);
    }
  }
#pragma unroll
  for (int i = 0; i < 4; ++i) {
    int n = tn * 4 + i;
#pragma unroll
    for (int j = 0; j < 4; ++j) {
      int h = h0 + th * 4 + j;
      ws[OFF_WO + ((size_t)br * N + n) * H + h] = acc[i][j] + ws[OFF_QP + br * H + h];
    }
  }
}

// grid (40, 4) x 256: h_prime[br] = attn[br] @ w_original[br], then ELU.
__global__ void k_hprime(const float* __restrict__ ws, float* __restrict__ out) {
  int br = blockIdx.x;
  int h = blockIdx.y * 128 + (threadIdx.x & 127);
  int ig = threadIdx.x >> 7;  // 0 or 1: which half of the 64 output rows
  __shared__ float sAtt[64 * 64];
  const float* att = ws + OFF_SC + (size_t)br * NE;
  for (int idx = threadIdx.x; idx < 4096; idx += 256) sAtt[idx] = att[idx];
  __syncthreads();
  float acc[32] = {};
  const float* wo = ws + OFF_WO + (size_t)br * N * H;
#pragma unroll 4
  for (int j = 0; j < 64; ++j) {
    float wv = wo[(size_t)j * H + h];
#pragma unroll
    for (int ii = 0; ii < 32; ++ii)
      acc[ii] = fmaf(sAtt[(ig * 32 + ii) * 64 + j], wv, acc[ii]);
  }
#pragma unroll
  for (int ii = 0; ii < 32; ++ii) {
    int i = ig * 32 + ii;
    float x = acc[ii];
    out[((size_t)br * N + i) * H + h] = x > 0.f ? x : expm1f(x);
  }
}

extern "C" void kernel_launch(void* const* d_in, const int* in_sizes, int n_in,
                              void* d_out, int out_size, void* d_ws, size_t ws_size,
                              hipStream_t stream) {
  const float* adj  = (const float*)d_in[0];
  const float* orig = (const float*)d_in[1];
  const float* ques = (const float*)d_in[2];
  const float* W    = (const float*)d_in[3];
  const float* a    = (const float*)d_in[4];
  float* out = (float*)d_out;
  float* ws  = (float*)d_ws;

  k_vecs<<<dim3(D + H), dim3(64), 0, stream>>>(W, a, ws);
  k_qproj<<<dim3(BR), dim3(512), 0, stream>>>(ques, W, ws);
  k_scores1<<<dim3(BR), dim3(256), 0, stream>>>(orig, ws);
  k_scores2<<<dim3(S / 4), dim3(256), 0, stream>>>(adj, ws);
  k_softmax<<<dim3(B * NE / 256), dim3(256), 0, stream>>>(ws);
  k_wo<<<dim3(BR, 8), dim3(256), 0, stream>>>(orig, W, ws);
  k_hprime<<<dim3(BR, 4), dim3(256), 0, stream>>>(ws, out);
}

// Round 7
// 188.121 us; speedup vs baseline: 1.2501x; 1.2501x over previous
//
#include <hip/hip_runtime.h>
#include <math.h>

namespace {
constexpr int B = 4, R = 10, N = 64, E = 64, D = 300, H = 512;
constexpr int BR = B * R;        // 40
constexpr int NE = N * E;        // 4096
constexpr int S = BR * NE;       // 163840
constexpr float SLOPE = 0.2f;

// ws layout (floats)
constexpr int OFF_V1  = 0;                 // 300   Wn @ a1
constexpr int OFF_V2  = OFF_V1 + 300;      // 300   Wn @ a2   (byte 1200, 16B-aligned)
constexpr int OFF_U1  = OFF_V2 + 300;      // 512   Wq @ a1
constexpr int OFF_U2  = OFF_U1 + H;        // 512   Wq @ a2
constexpr int OFF_QP  = OFF_U2 + H;        // 40*512 q_proj
constexpr int OFF_QA1 = OFF_QP + BR * H;   // 40
constexpr int OFF_QA2 = OFF_QA1 + BR;      // 40
constexpr int OFF_SC  = OFF_QA2 + BR;      // 163840 attn (written post-softmax)
constexpr int OFF_WO  = OFF_SC + S;        // 1310720 w_original
}

__device__ inline float waveReduce(float v) {
#pragma unroll
  for (int o = 32; o > 0; o >>= 1) v += __shfl_xor(v, o, 64);
  return v;
}

// grid 812 x 64: one wave per W row; dot with a1 and a2.
__global__ __launch_bounds__(64) void k_vecs(const float* __restrict__ W,
                                             const float* __restrict__ a,
                                             float* __restrict__ ws) {
  int row = blockIdx.x;
  int lane = threadIdx.x;
  const float4* rf  = reinterpret_cast<const float4*>(W + (size_t)row * H);
  const float4* a1f = reinterpret_cast<const float4*>(a);
  const float4* a2f = reinterpret_cast<const float4*>(a + H);
  float4 x0 = rf[lane], x1 = rf[64 + lane];
  float4 p0 = a1f[lane], p1 = a1f[64 + lane];
  float4 q0 = a2f[lane], q1 = a2f[64 + lane];
  float s1 = x0.x * p0.x + x0.y * p0.y + x0.z * p0.z + x0.w * p0.w
           + x1.x * p1.x + x1.y * p1.y + x1.z * p1.z + x1.w * p1.w;
  float s2 = x0.x * q0.x + x0.y * q0.y + x0.z * q0.z + x0.w * q0.w
           + x1.x * q1.x + x1.y * q1.y + x1.z * q1.z + x1.w * q1.w;
  s1 = waveReduce(s1);
  s2 = waveReduce(s2);
  if (lane == 0) {
    if (row < D) { ws[OFF_V1 + row] = s1; ws[OFF_V2 + row] = s2; }
    else         { ws[OFF_U1 + (row - D)] = s1; ws[OFF_U2 + (row - D)] = s2; }
  }
}

// grid 40 x 512: q_proj row + qa1/qa2 scalars.
__global__ __launch_bounds__(512) void k_qproj(const float* __restrict__ ques,
                                               const float* __restrict__ W,
                                               float* __restrict__ ws) {
  int br = blockIdx.x, h = threadIdx.x;
  __shared__ float qs[H];
  __shared__ float red[16];
  qs[h] = ques[(size_t)br * H + h];
  __syncthreads();
  float acc = 0.f;
#pragma unroll 8
  for (int q = 0; q < H; ++q) acc = fmaf(qs[q], W[(size_t)(D + q) * H + h], acc);
  ws[OFF_QP + br * H + h] = acc;
  float p1 = qs[h] * ws[OFF_U1 + h];
  float p2 = qs[h] * ws[OFF_U2 + h];
  p1 = waveReduce(p1);
  p2 = waveReduce(p2);
  int lane = h & 63, w = h >> 6;
  if (lane == 0) { red[w] = p1; red[8 + w] = p2; }
  __syncthreads();
  if (h == 0) {
    float t1 = 0.f, t2 = 0.f;
#pragma unroll
    for (int i = 0; i < 8; ++i) { t1 += red[i]; t2 += red[8 + i]; }
    ws[OFF_QA1 + br] = t1;
    ws[OFF_QA2 + br] = t2;
  }
}

// grid 256 x 512: one block per (b,n). Fuses scores1+scores2+leaky+softmax,
// writes attn directly. 650 row-dots per block (640 adj + 10 orig).
__global__ __launch_bounds__(512) void k_attn(const float* __restrict__ adj,
                                              const float* __restrict__ orig,
                                              float* __restrict__ ws) {
  int bn = blockIdx.x;
  int b = bn >> 6, n = bn & 63;
  int wave = threadIdx.x >> 6, lane = threadIdx.x & 63;
  __shared__ float s_sc[R * E];   // adj-row dots
  __shared__ float s_o[R];        // orig-row dots
  __shared__ float q1l[R], q2l[R];
  if (threadIdx.x < R) {
    q1l[threadIdx.x] = ws[OFF_QA1 + b * R + threadIdx.x];
    q2l[threadIdx.x] = ws[OFF_QA2 + b * R + threadIdx.x];
  }
  const float4* v1f = reinterpret_cast<const float4*>(ws + OFF_V1);
  const float4* v2f = reinterpret_cast<const float4*>(ws + OFF_V2);
  float4 va2 = v2f[lane];
  float4 vb2 = (lane < 11) ? v2f[64 + lane] : make_float4(0.f, 0.f, 0.f, 0.f);
  float4 va1 = v1f[lane];
  float4 vb1 = (lane < 11) ? v1f[64 + lane] : make_float4(0.f, 0.f, 0.f, 0.f);
  const size_t adj_base  = ((size_t)(b * R) * N + n) * E * D;  // + r*N*E*D + e*D
  const size_t orig_base = ((size_t)(b * R) * N + n) * D;      // + r*N*D

  for (int row = wave; row < R * E + R; row += 8) {
    const float* rp;
    float4 va, vb;
    bool isadj = row < R * E;
    if (isadj) {
      int r = row >> 6, e = row & 63;
      rp = adj + adj_base + (size_t)r * N * E * D + (size_t)e * D;
      va = va2; vb = vb2;
    } else {
      int r = row - R * E;
      rp = orig + orig_base + (size_t)r * N * D;
      va = va1; vb = vb1;
    }
    const float4* rf = reinterpret_cast<const float4*>(rp);
    float4 x = rf[lane];
    float acc = x.x * va.x + x.y * va.y + x.z * va.z + x.w * va.w;
    if (lane < 11) {
      float4 y = rf[64 + lane];
      acc += y.x * vb.x + y.y * vb.y + y.z * vb.z + y.w * vb.w;
    }
    acc = waveReduce(acc);
    if (lane == 0) {
      if (isadj) s_sc[row] = acc;
      else       s_o[row - R * E] = acc;
    }
  }
  __syncthreads();
  if (threadIdx.x < E) {
    int e = threadIdx.x;
    float v[R];
    float m = -1e30f;
#pragma unroll
    for (int r = 0; r < R; ++r) {
      float sc = s_sc[r * E + e] + s_o[r] + q1l[r] + q2l[r];
      sc = sc > 0.f ? sc : SLOPE * sc;
      v[r] = sc;
      m = fmaxf(m, sc);
    }
    float ssum = 0.f;
#pragma unroll
    for (int r = 0; r < R; ++r) { v[r] = __expf(v[r] - m); ssum += v[r]; }
    float inv = 1.f / ssum;
#pragma unroll
    for (int r = 0; r < R; ++r)
      ws[OFF_SC + ((size_t)(b * R + r) * N + n) * E + e] = v[r] * inv;
  }
}

// grid (40, 8) x 256: w_original[br] = orig[br] @ Wn + q_proj[br]
__global__ __launch_bounds__(256) void k_wo(const float* __restrict__ orig,
                                            const float* __restrict__ W,
                                            float* __restrict__ ws) {
  int br = blockIdx.x, h0 = blockIdx.y * 64;
  int t = threadIdx.x;
  __shared__ __align__(16) float sA[64 * 60];
  __shared__ __align__(16) float sB[60 * 64];
  const float4* sBf = reinterpret_cast<const float4*>(sB);
  int tn = t >> 4, th = t & 15;
  float acc[4][4] = {};
  for (int k0 = 0; k0 < D; k0 += 60) {
    __syncthreads();
    for (int idx = t; idx < 64 * 60; idx += 256) {
      int n = idx / 60, kk = idx % 60;
      sA[idx] = orig[((size_t)br * N + n) * D + k0 + kk];
    }
    for (int idx = t; idx < 60 * 64; idx += 256) {
      int kk = idx >> 6, hh = idx & 63;
      sB[idx] = W[(size_t)(k0 + kk) * H + h0 + hh];
    }
    __syncthreads();
#pragma unroll 4
    for (int kk = 0; kk < 60; ++kk) {
      float av[4];
#pragma unroll
      for (int i = 0; i < 4; ++i) av[i] = sA[(tn * 4 + i) * 60 + kk];
      float4 bv = sBf[kk * 16 + th];
#pragma unroll
      for (int i = 0; i < 4; ++i) {
        acc[i][0] = fmaf(av[i], bv.x, acc[i][0]);
        acc[i][1] = fmaf(av[i], bv.y, acc[i][1]);
        acc[i][2] = fmaf(av[i], bv.z, acc[i][2]);
        acc[i][3] = fmaf(av[i], bv.w, acc[i][3]);
      }
    }
  }
#pragma unroll
  for (int i = 0; i < 4; ++i) {
    int n = tn * 4 + i;
#pragma unroll
    for (int j = 0; j < 4; ++j) {
      int h = h0 + th * 4 + j;
      ws[OFF_WO + ((size_t)br * N + n) * H + h] = acc[i][j] + ws[OFF_QP + br * H + h];
    }
  }
}

// grid (40, 4) x 256: h_prime[br] = attn[br] @ w_original[br], then ELU.
__global__ __launch_bounds__(256) void k_hprime(const float* __restrict__ ws,
                                                float* __restrict__ out) {
  int br = blockIdx.x;
  int h = blockIdx.y * 128 + (threadIdx.x & 127);
  int ig = threadIdx.x >> 7;
  __shared__ __align__(16) float sAtt[64 * 64];
  const float* att = ws + OFF_SC + (size_t)br * NE;
  for (int idx = threadIdx.x; idx < 4096; idx += 256) sAtt[idx] = att[idx];
  __syncthreads();
  float acc[32] = {};
  const float* wo = ws + OFF_WO + (size_t)br * N * H;
  const float4* sAttf = reinterpret_cast<const float4*>(sAtt);
#pragma unroll 2
  for (int j4 = 0; j4 < 16; ++j4) {
    float w0 = wo[(size_t)(4 * j4 + 0) * H + h];
    float w1 = wo[(size_t)(4 * j4 + 1) * H + h];
    float w2 = wo[(size_t)(4 * j4 + 2) * H + h];
    float w3 = wo[(size_t)(4 * j4 + 3) * H + h];
#pragma unroll
    for (int ii = 0; ii < 32; ++ii) {
      float4 a4 = sAttf[(ig * 32 + ii) * 16 + j4];
      acc[ii] = fmaf(a4.x, w0, fmaf(a4.y, w1, fmaf(a4.z, w2, fmaf(a4.w, w3, acc[ii]))));
    }
  }
#pragma unroll
  for (int ii = 0; ii < 32; ++ii) {
    int i = ig * 32 + ii;
    float x = acc[ii];
    out[((size_t)br * N + i) * H + h] = x > 0.f ? x : expm1f(x);
  }
}

extern "C" void kernel_launch(void* const* d_in, const int* in_sizes, int n_in,
                              void* d_out, int out_size, void* d_ws, size_t ws_size,
                              hipStream_t stream) {
  const float* adj  = (const float*)d_in[0];
  const float* orig = (const float*)d_in[1];
  const float* ques = (const float*)d_in[2];
  const float* W    = (const float*)d_in[3];
  const float* a    = (const float*)d_in[4];
  float* out = (float*)d_out;
  float* ws  = (float*)d_ws;

  k_vecs<<<dim3(D + H), dim3(64), 0, stream>>>(W, a, ws);
  k_qproj<<<dim3(BR), dim3(512), 0, stream>>>(ques, W, ws);
  k_attn<<<dim3(B * N), dim3(512), 0, stream>>>(adj, orig, ws);
  k_wo<<<dim3(BR, 8), dim3(256), 0, stream>>>(orig, W, ws);
  k_hprime<<<dim3(BR, 4), dim3(256), 0, stream>>>(ws, out);
}

// Round 8
// 152.756 us; speedup vs baseline: 1.5396x; 1.2315x over previous
//
#include <hip/hip_runtime.h>
#include <math.h>

namespace {
constexpr int B = 4, R = 10, N = 64, E = 64, D = 300, H = 512;
constexpr int BR = B * R;        // 40
constexpr int NE = N * E;        // 4096
constexpr int S = BR * NE;       // 163840
constexpr float SLOPE = 0.2f;

// ws layout (floats)
constexpr int OFF_V1  = 0;                 // 300   Wn @ a1
constexpr int OFF_V2  = OFF_V1 + 300;      // 300   Wn @ a2  (byte 1200, 16B-aligned)
constexpr int OFF_U1  = OFF_V2 + 300;      // 512   Wq @ a1
constexpr int OFF_U2  = OFF_U1 + H;        // 512   Wq @ a2
constexpr int OFF_QP  = OFF_U2 + H;        // 40*512 q_proj
constexpr int OFF_QA1 = OFF_QP + BR * H;   // 40
constexpr int OFF_QA2 = OFF_QA1 + BR;      // 40
constexpr int OFF_S1  = OFF_QA2 + BR;      // 2560  scores1[b,r,n] (incl. qa1)
constexpr int OFF_RAW = OFF_S1 + BR * N;   // 163840 raw adj.v2 dots
constexpr int OFF_SC  = OFF_RAW + S;       // 163840 attn (post-softmax)
constexpr int OFF_WO  = OFF_SC + S;        // 1310720 w_original
// total ~1.66M floats = 6.65 MB
}

__device__ inline float waveReduce(float v) {
#pragma unroll
  for (int o = 32; o > 0; o >>= 1) v += __shfl_xor(v, o, 64);
  return v;
}

__device__ inline float dot4(float4 a, float4 b) {
  return a.x * b.x + a.y * b.y + a.z * b.z + a.w * b.w;
}

// grid 812 x 64: one wave per W row; dot with a1 and a2.
__global__ __launch_bounds__(64) void k_vecs(const float* __restrict__ W,
                                             const float* __restrict__ a,
                                             float* __restrict__ ws) {
  int row = blockIdx.x;
  int lane = threadIdx.x;
  const float4* rf  = reinterpret_cast<const float4*>(W + (size_t)row * H);
  const float4* a1f = reinterpret_cast<const float4*>(a);
  const float4* a2f = reinterpret_cast<const float4*>(a + H);
  float4 x0 = rf[lane], x1 = rf[64 + lane];
  float4 p0 = a1f[lane], p1 = a1f[64 + lane];
  float4 q0 = a2f[lane], q1 = a2f[64 + lane];
  float s1 = dot4(x0, p0) + dot4(x1, p1);
  float s2 = dot4(x0, q0) + dot4(x1, q1);
  s1 = waveReduce(s1);
  s2 = waveReduce(s2);
  if (lane == 0) {
    if (row < D) { ws[OFF_V1 + row] = s1; ws[OFF_V2 + row] = s2; }
    else         { ws[OFF_U1 + (row - D)] = s1; ws[OFF_U2 + (row - D)] = s2; }
  }
}

// grid 40 x 512: q_proj row + qa1/qa2 scalars.
__global__ __launch_bounds__(512) void k_qproj(const float* __restrict__ ques,
                                               const float* __restrict__ W,
                                               float* __restrict__ ws) {
  int br = blockIdx.x, h = threadIdx.x;
  __shared__ float qs[H];
  __shared__ float red[16];
  qs[h] = ques[(size_t)br * H + h];
  __syncthreads();
  float acc = 0.f;
#pragma unroll 8
  for (int q = 0; q < H; ++q) acc = fmaf(qs[q], W[(size_t)(D + q) * H + h], acc);
  ws[OFF_QP + br * H + h] = acc;
  float p1 = qs[h] * ws[OFF_U1 + h];
  float p2 = qs[h] * ws[OFF_U2 + h];
  p1 = waveReduce(p1);
  p2 = waveReduce(p2);
  int lane = h & 63, w = h >> 6;
  if (lane == 0) { red[w] = p1; red[8 + w] = p2; }
  __syncthreads();
  if (h == 0) {
    float t1 = 0.f, t2 = 0.f;
#pragma unroll
    for (int i = 0; i < 8; ++i) { t1 += red[i]; t2 += red[8 + i]; }
    ws[OFF_QA1 + br] = t1;
    ws[OFF_QA2 + br] = t2;
  }
}

// grid 40 x 256 (4 waves): s1[br,n] = orig[br,n,:].v1 + qa1[br]
__global__ __launch_bounds__(256) void k_scores1(const float* __restrict__ orig,
                                                 float* __restrict__ ws) {
  int br = blockIdx.x;
  int wave = threadIdx.x >> 6, lane = threadIdx.x & 63;
  const float4* vf = reinterpret_cast<const float4*>(ws + OFF_V1);
  float4 va = vf[lane];
  float4 vb = (lane < 11) ? vf[64 + lane] : make_float4(0.f, 0.f, 0.f, 0.f);
  float qa1 = ws[OFF_QA1 + br];
  for (int n = wave; n < N; n += 4) {
    const float4* rf = reinterpret_cast<const float4*>(orig + ((size_t)br * N + n) * D);
    float acc = dot4(rf[lane], va);
    if (lane < 11) acc += dot4(rf[64 + lane], vb);
    acc = waveReduce(acc);
    if (lane == 0) ws[OFF_S1 + br * N + n] = acc + qa1;
  }
}

// grid 5120 x 512: each wave computes 4 consecutive adj-row dots against v2.
// 8 independent global loads issued up front (one HBM latency covers all),
// then 4 interleaved shfl-reduce chains (ILP). No LDS -> high occupancy.
__global__ __launch_bounds__(512) void k_scores2(const float* __restrict__ adj,
                                                 float* __restrict__ ws) {
  int wid = blockIdx.x * 8 + (threadIdx.x >> 6);   // 0..40959
  int lane = threadIdx.x & 63;
  size_t r0 = (size_t)wid * 4;
  const float4* vf = reinterpret_cast<const float4*>(ws + OFF_V2);
  float4 va = vf[lane];
  float4 vb = (lane < 11) ? vf[64 + lane] : make_float4(0.f, 0.f, 0.f, 0.f);
  const float4* p0 = reinterpret_cast<const float4*>(adj + (r0 + 0) * D);
  const float4* p1 = reinterpret_cast<const float4*>(adj + (r0 + 1) * D);
  const float4* p2 = reinterpret_cast<const float4*>(adj + (r0 + 2) * D);
  const float4* p3 = reinterpret_cast<const float4*>(adj + (r0 + 3) * D);
  // main 256 elements per row
  float4 x0 = p0[lane], x1 = p1[lane], x2 = p2[lane], x3 = p3[lane];
  float a0 = dot4(x0, va), a1 = dot4(x1, va), a2 = dot4(x2, va), a3 = dot4(x3, va);
  // tail 44 elements per row (lanes 0..10)
  if (lane < 11) {
    float4 y0 = p0[64 + lane], y1 = p1[64 + lane];
    float4 y2 = p2[64 + lane], y3 = p3[64 + lane];
    a0 += dot4(y0, vb); a1 += dot4(y1, vb);
    a2 += dot4(y2, vb); a3 += dot4(y3, vb);
  }
#pragma unroll
  for (int o = 32; o > 0; o >>= 1) {
    a0 += __shfl_xor(a0, o, 64);
    a1 += __shfl_xor(a1, o, 64);
    a2 += __shfl_xor(a2, o, 64);
    a3 += __shfl_xor(a3, o, 64);
  }
  float v = (lane == 0) ? a0 : (lane == 1) ? a1 : (lane == 2) ? a2 : a3;
  if (lane < 4) ws[OFF_RAW + r0 + lane] = v;
}

// grid 64 x 256: per (b,n,e): add s1+qa2, leaky-relu, softmax over r, write attn.
__global__ __launch_bounds__(256) void k_softmax(float* __restrict__ ws) {
  int t = blockIdx.x * 256 + threadIdx.x;  // 0..16383 = B*N*E
  int b = t >> 12;
  int ne = t & 4095;
  int n = ne >> 6;
  const float* raw = ws + OFF_RAW;
  float v[R];
  float m = -1e30f;
#pragma unroll
  for (int r = 0; r < R; ++r) {
    int br = b * R + r;
    float sc = raw[(size_t)br * NE + ne] + ws[OFF_QA2 + br] + ws[OFF_S1 + br * N + n];
    sc = sc > 0.f ? sc : SLOPE * sc;
    v[r] = sc;
    m = fmaxf(m, sc);
  }
  float s = 0.f;
#pragma unroll
  for (int r = 0; r < R; ++r) { v[r] = __expf(v[r] - m); s += v[r]; }
  float inv = 1.f / s;
#pragma unroll
  for (int r = 0; r < R; ++r)
    ws[OFF_SC + (size_t)(b * R + r) * NE + ne] = v[r] * inv;
}

// grid (40, 8) x 256: w_original[br] = orig[br] @ Wn + q_proj[br]
__global__ __launch_bounds__(256) void k_wo(const float* __restrict__ orig,
                                            const float* __restrict__ W,
                                            float* __restrict__ ws) {
  int br = blockIdx.x, h0 = blockIdx.y * 64;
  int t = threadIdx.x;
  __shared__ __align__(16) float sA[64 * 60];
  __shared__ __align__(16) float sB[60 * 64];
  const float4* sBf = reinterpret_cast<const float4*>(sB);
  int tn = t >> 4, th = t & 15;
  float acc[4][4] = {};
  for (int k0 = 0; k0 < D; k0 += 60) {
    __syncthreads();
    for (int idx = t; idx < 64 * 60; idx += 256) {
      int n = idx / 60, kk = idx % 60;
      sA[idx] = orig[((size_t)br * N + n) * D + k0 + kk];
    }
    for (int idx = t; idx < 60 * 64; idx += 256) {
      int kk = idx >> 6, hh = idx & 63;
      sB[idx] = W[(size_t)(k0 + kk) * H + h0 + hh];
    }
    __syncthreads();
#pragma unroll 4
    for (int kk = 0; kk < 60; ++kk) {
      float av[4];
#pragma unroll
      for (int i = 0; i < 4; ++i) av[i] = sA[(tn * 4 + i) * 60 + kk];
      float4 bv = sBf[kk * 16 + th];
#pragma unroll
      for (int i = 0; i < 4; ++i) {
        acc[i][0] = fmaf(av[i], bv.x, acc[i][0]);
        acc[i][1] = fmaf(av[i], bv.y, acc[i][1]);
        acc[i][2] = fmaf(av[i], bv.z, acc[i][2]);
        acc[i][3] = fmaf(av[i], bv.w, acc[i][3]);
      }
    }
  }
#pragma unroll
  for (int i = 0; i < 4; ++i) {
    int n = tn * 4 + i;
#pragma unroll
    for (int j = 0; j < 4; ++j) {
      int h = h0 + th * 4 + j;
      ws[OFF_WO + ((size_t)br * N + n) * H + h] = acc[i][j] + ws[OFF_QP + br * H + h];
    }
  }
}

// grid (40, 4) x 256: h_prime[br] = attn[br] @ w_original[br], then ELU.
__global__ __launch_bounds__(256) void k_hprime(const float* __restrict__ ws,
                                                float* __restrict__ out) {
  int br = blockIdx.x;
  int h = blockIdx.y * 128 + (threadIdx.x & 127);
  int ig = threadIdx.x >> 7;
  __shared__ __align__(16) float sAtt[64 * 64];
  const float* att = ws + OFF_SC + (size_t)br * NE;
  for (int idx = threadIdx.x; idx < 4096; idx += 256) sAtt[idx] = att[idx];
  __syncthreads();
  float acc[32] = {};
  const float* wo = ws + OFF_WO + (size_t)br * N * H;
  const float4* sAttf = reinterpret_cast<const float4*>(sAtt);
#pragma unroll 2
  for (int j4 = 0; j4 < 16; ++j4) {
    float w0 = wo[(size_t)(4 * j4 + 0) * H + h];
    float w1 = wo[(size_t)(4 * j4 + 1) * H + h];
    float w2 = wo[(size_t)(4 * j4 + 2) * H + h];
    float w3 = wo[(size_t)(4 * j4 + 3) * H + h];
#pragma unroll
    for (int ii = 0; ii < 32; ++ii) {
      float4 a4 = sAttf[(ig * 32 + ii) * 16 + j4];
      acc[ii] = fmaf(a4.x, w0, fmaf(a4.y, w1, fmaf(a4.z, w2, fmaf(a4.w, w3, acc[ii]))));
    }
  }
#pragma unroll
  for (int ii = 0; ii < 32; ++ii) {
    int i = ig * 32 + ii;
    float x = acc[ii];
    out[((size_t)br * N + i) * H + h] = x > 0.f ? x : expm1f(x);
  }
}

extern "C" void kernel_launch(void* const* d_in, const int* in_sizes, int n_in,
                              void* d_out, int out_size, void* d_ws, size_t ws_size,
                              hipStream_t stream) {
  const float* adj  = (const float*)d_in[0];
  const float* orig = (const float*)d_in[1];
  const float* ques = (const float*)d_in[2];
  const float* W    = (const float*)d_in[3];
  const float* a    = (const float*)d_in[4];
  float* out = (float*)d_out;
  float* ws  = (float*)d_ws;

  k_vecs<<<dim3(D + H), dim3(64), 0, stream>>>(W, a, ws);
  k_qproj<<<dim3(BR), dim3(512), 0, stream>>>(ques, W, ws);
  k_scores1<<<dim3(BR), dim3(256), 0, stream>>>(orig, ws);
  k_scores2<<<dim3(S / 32), dim3(512), 0, stream>>>(adj, ws);   // 5120 blocks
  k_softmax<<<dim3(B * NE / 256), dim3(256), 0, stream>>>(ws);
  k_wo<<<dim3(BR, 8), dim3(256), 0, stream>>>(orig, W, ws);
  k_hprime<<<dim3(BR, 4), dim3(256), 0, stream>>>(ws, out);
}

// Round 10
// 147.211 us; speedup vs baseline: 1.5976x; 1.0377x over previous
//
#include <hip/hip_runtime.h>
#include <math.h>

namespace {
constexpr int B = 4, R = 10, N = 64, E = 64, D = 300, H = 512;
constexpr int BR = B * R;        // 40
constexpr int NE = N * E;        // 4096
constexpr int S = BR * NE;       // 163840
constexpr float SLOPE = 0.2f;

// ws layout (floats)
constexpr int OFF_V1  = 0;                 // 300   Wn @ a1
constexpr int OFF_V2  = OFF_V1 + 300;      // 300   Wn @ a2  (byte 1200, 16B-aligned)
constexpr int OFF_U1  = OFF_V2 + 300;      // 512   Wq @ a1
constexpr int OFF_U2  = OFF_U1 + H;        // 512   Wq @ a2
constexpr int OFF_QP  = OFF_U2 + H;        // 40*512 q_proj
constexpr int OFF_QA1 = OFF_QP + BR * H;   // 40
constexpr int OFF_QA2 = OFF_QA1 + BR;      // 40
constexpr int OFF_S1  = OFF_QA2 + BR;      // 2560  scores1[b,r,n] (incl. qa1)
constexpr int OFF_RAW = OFF_S1 + BR * N;   // 163840 raw adj.v2 dots
constexpr int OFF_SC  = OFF_RAW + S;       // 163840 attn (post-softmax)
constexpr int OFF_WO  = OFF_SC + S;        // 1310720 w_original
// total ~1.66M floats = 6.65 MB
}

__device__ inline float waveReduce(float v) {
#pragma unroll
  for (int o = 32; o > 0; o >>= 1) v += __shfl_xor(v, o, 64);
  return v;
}

__device__ inline float dot4(float4 a, float4 b) {
  return a.x * b.x + a.y * b.y + a.z * b.z + a.w * b.w;
}

// grid 812 x 64: one wave per W row; dot with a1 and a2.
__global__ __launch_bounds__(64) void k_vecs(const float* __restrict__ W,
                                             const float* __restrict__ a,
                                             float* __restrict__ ws) {
  int row = blockIdx.x;
  int lane = threadIdx.x;
  const float4* rf  = reinterpret_cast<const float4*>(W + (size_t)row * H);
  const float4* a1f = reinterpret_cast<const float4*>(a);
  const float4* a2f = reinterpret_cast<const float4*>(a + H);
  float4 x0 = rf[lane], x1 = rf[64 + lane];
  float4 p0 = a1f[lane], p1 = a1f[64 + lane];
  float4 q0 = a2f[lane], q1 = a2f[64 + lane];
  float s1 = dot4(x0, p0) + dot4(x1, p1);
  float s2 = dot4(x0, q0) + dot4(x1, q1);
  s1 = waveReduce(s1);
  s2 = waveReduce(s2);
  if (lane == 0) {
    if (row < D) { ws[OFF_V1 + row] = s1; ws[OFF_V2 + row] = s2; }
    else         { ws[OFF_U1 + (row - D)] = s1; ws[OFF_U2 + (row - D)] = s2; }
  }
}

// grid 40 x 512: q_proj row + qa1/qa2 scalars + scores1 (fused).
__global__ __launch_bounds__(512) void k_qproj_s1(const float* __restrict__ ques,
                                                  const float* __restrict__ W,
                                                  const float* __restrict__ orig,
                                                  float* __restrict__ ws) {
  int br = blockIdx.x, h = threadIdx.x;
  __shared__ float qs[H];
  __shared__ float red[16];
  __shared__ float qa1s;
  qs[h] = ques[(size_t)br * H + h];
  __syncthreads();
  float acc = 0.f;
#pragma unroll 8
  for (int q = 0; q < H; ++q) acc = fmaf(qs[q], W[(size_t)(D + q) * H + h], acc);
  ws[OFF_QP + br * H + h] = acc;
  float p1 = qs[h] * ws[OFF_U1 + h];
  float p2 = qs[h] * ws[OFF_U2 + h];
  p1 = waveReduce(p1);
  p2 = waveReduce(p2);
  int lane = h & 63, wave = h >> 6;
  if (lane == 0) { red[wave] = p1; red[8 + wave] = p2; }
  __syncthreads();
  if (h == 0) {
    float t1 = 0.f, t2 = 0.f;
#pragma unroll
    for (int i = 0; i < 8; ++i) { t1 += red[i]; t2 += red[8 + i]; }
    ws[OFF_QA1 + br] = t1;
    ws[OFF_QA2 + br] = t2;
    qa1s = t1;
  }
  __syncthreads();
  // scores1: 64 orig-row dots against v1, 8 waves x 8 rows.
  float qa1 = qa1s;
  const float4* vf = reinterpret_cast<const float4*>(ws + OFF_V1);
  float4 va = vf[lane];
  float4 vb = (lane < 11) ? vf[64 + lane] : make_float4(0.f, 0.f, 0.f, 0.f);
  for (int n = wave; n < N; n += 8) {
    const float4* rf = reinterpret_cast<const float4*>(orig + ((size_t)br * N + n) * D);
    float a0 = dot4(rf[lane], va);
    if (lane < 11) a0 += dot4(rf[64 + lane], vb);
    a0 = waveReduce(a0);
    if (lane == 0) ws[OFF_S1 + br * N + n] = a0 + qa1;
  }
}

// grid 5120 x 512: each wave computes 4 consecutive adj-row dots against v2.
// 8 independent global loads issued up front (one HBM latency covers all),
// then 4 interleaved shfl-reduce chains (ILP). No LDS -> high occupancy.
__global__ __launch_bounds__(512) void k_scores2(const float* __restrict__ adj,
                                                 float* __restrict__ ws) {
  int wid = blockIdx.x * 8 + (threadIdx.x >> 6);   // 0..40959
  int lane = threadIdx.x & 63;
  size_t r0 = (size_t)wid * 4;
  const float4* vf = reinterpret_cast<const float4*>(ws + OFF_V2);
  float4 va = vf[lane];
  float4 vb = (lane < 11) ? vf[64 + lane] : make_float4(0.f, 0.f, 0.f, 0.f);
  const float4* p0 = reinterpret_cast<const float4*>(adj + (r0 + 0) * D);
  const float4* p1 = reinterpret_cast<const float4*>(adj + (r0 + 1) * D);
  const float4* p2 = reinterpret_cast<const float4*>(adj + (r0 + 2) * D);
  const float4* p3 = reinterpret_cast<const float4*>(adj + (r0 + 3) * D);
  float4 x0 = p0[lane], x1 = p1[lane], x2 = p2[lane], x3 = p3[lane];
  float a0 = dot4(x0, va), a1 = dot4(x1, va), a2 = dot4(x2, va), a3 = dot4(x3, va);
  if (lane < 11) {
    float4 y0 = p0[64 + lane], y1 = p1[64 + lane];
    float4 y2 = p2[64 + lane], y3 = p3[64 + lane];
    a0 += dot4(y0, vb); a1 += dot4(y1, vb);
    a2 += dot4(y2, vb); a3 += dot4(y3, vb);
  }
#pragma unroll
  for (int o = 32; o > 0; o >>= 1) {
    a0 += __shfl_xor(a0, o, 64);
    a1 += __shfl_xor(a1, o, 64);
    a2 += __shfl_xor(a2, o, 64);
    a3 += __shfl_xor(a3, o, 64);
  }
  float v = (lane == 0) ? a0 : (lane == 1) ? a1 : (lane == 2) ? a2 : a3;
  if (lane < 4) ws[OFF_RAW + r0 + lane] = v;
}

// grid 384 x 256, block-split fusion of two independent kernels:
//   blocks 0..63:  softmax over r per (b,n,e) -> attn
//   blocks 64..383: w_original tile GEMM (br, h0)
__global__ __launch_bounds__(256) void k_soft_wo(const float* __restrict__ orig,
                                                 const float* __restrict__ W,
                                                 float* __restrict__ ws) {
  __shared__ __align__(16) float sA[64 * 60];
  __shared__ __align__(16) float sB[60 * 64];
  if (blockIdx.x < 64) {
    // ---- softmax path ----
    int t = blockIdx.x * 256 + threadIdx.x;  // 0..16383 = B*N*E
    int b = t >> 12;
    int ne = t & 4095;
    int n = ne >> 6;
    const float* raw = ws + OFF_RAW;
    float v[R];
    float m = -1e30f;
#pragma unroll
    for (int r = 0; r < R; ++r) {
      int br = b * R + r;
      float sc = raw[(size_t)br * NE + ne] + ws[OFF_QA2 + br] + ws[OFF_S1 + br * N + n];
      sc = sc > 0.f ? sc : SLOPE * sc;
      v[r] = sc;
      m = fmaxf(m, sc);
    }
    float s = 0.f;
#pragma unroll
    for (int r = 0; r < R; ++r) { v[r] = __expf(v[r] - m); s += v[r]; }
    float inv = 1.f / s;
#pragma unroll
    for (int r = 0; r < R; ++r)
      ws[OFF_SC + (size_t)(b * R + r) * NE + ne] = v[r] * inv;
    return;
  }
  // ---- w_original tile GEMM path ----
  int bi = blockIdx.x - 64;          // 0..319
  int br = bi >> 3, h0 = (bi & 7) * 64;
  int t = threadIdx.x;
  const float4* sBf = reinterpret_cast<const float4*>(sB);
  int tn = t >> 4, th = t & 15;
  float acc[4][4] = {};
  for (int k0 = 0; k0 < D; k0 += 60) {
    __syncthreads();
    for (int idx = t; idx < 64 * 60; idx += 256) {
      int n = idx / 60, kk = idx % 60;
      sA[idx] = orig[((size_t)br * N + n) * D + k0 + kk];
    }
    for (int idx = t; idx < 60 * 64; idx += 256) {
      int kk = idx >> 6, hh = idx & 63;
      sB[idx] = W[(size_t)(k0 + kk) * H + h0 + hh];
    }
    __syncthreads();
#pragma unroll 4
    for (int kk = 0; kk < 60; ++kk) {
      float av[4];
#pragma unroll
      for (int i = 0; i < 4; ++i) av[i] = sA[(tn * 4 + i) * 60 + kk];
      float4 bv = sBf[kk * 16 + th];
#pragma unroll
      for (int i = 0; i < 4; ++i) {
        acc[i][0] = fmaf(av[i], bv.x, acc[i][0]);
        acc[i][1] = fmaf(av[i], bv.y, acc[i][1]);
        acc[i][2] = fmaf(av[i], bv.z, acc[i][2]);
        acc[i][3] = fmaf(av[i], bv.w, acc[i][3]);
      }
    }
  }
#pragma unroll
  for (int i = 0; i < 4; ++i) {
    int n = tn * 4 + i;
#pragma unroll
    for (int j = 0; j < 4; ++j) {
      int h = h0 + th * 4 + j;
      ws[OFF_WO + ((size_t)br * N + n) * H + h] = acc[i][j] + ws[OFF_QP + br * H + h];
    }
  }
}

// grid (40, 4) x 256: h_prime[br] = attn[br] @ w_original[br], then ELU.
__global__ __launch_bounds__(256) void k_hprime(const float* __restrict__ ws,
                                                float* __restrict__ out) {
  int br = blockIdx.x;
  int h = blockIdx.y * 128 + (threadIdx.x & 127);
  int ig = threadIdx.x >> 7;
  __shared__ __align__(16) float sAtt[64 * 64];
  const float* att = ws + OFF_SC + (size_t)br * NE;
  for (int idx = threadIdx.x; idx < 4096; idx += 256) sAtt[idx] = att[idx];
  __syncthreads();
  float acc[32] = {};
  const float* wo = ws + OFF_WO + (size_t)br * N * H;
  const float4* sAttf = reinterpret_cast<const float4*>(sAtt);
#pragma unroll 2
  for (int j4 = 0; j4 < 16; ++j4) {
    float w0 = wo[(size_t)(4 * j4 + 0) * H + h];
    float w1 = wo[(size_t)(4 * j4 + 1) * H + h];
    float w2 = wo[(size_t)(4 * j4 + 2) * H + h];
    float w3 = wo[(size_t)(4 * j4 + 3) * H + h];
#pragma unroll
    for (int ii = 0; ii < 32; ++ii) {
      float4 a4 = sAttf[(ig * 32 + ii) * 16 + j4];
      acc[ii] = fmaf(a4.x, w0, fmaf(a4.y, w1, fmaf(a4.z, w2, fmaf(a4.w, w3, acc[ii]))));
    }
  }
#pragma unroll
  for (int ii = 0; ii < 32; ++ii) {
    int i = ig * 32 + ii;
    float x = acc[ii];
    out[((size_t)br * N + i) * H + h] = x > 0.f ? x : expm1f(x);
  }
}

extern "C" void kernel_launch(void* const* d_in, const int* in_sizes, int n_in,
                              void* d_out, int out_size, void* d_ws, size_t ws_size,
                              hipStream_t stream) {
  const float* adj  = (const float*)d_in[0];
  const float* orig = (const float*)d_in[1];
  const float* ques = (const float*)d_in[2];
  const float* W    = (const float*)d_in[3];
  const float* a    = (const float*)d_in[4];
  float* out = (float*)d_out;
  float* ws  = (float*)d_ws;

  k_vecs<<<dim3(D + H), dim3(64), 0, stream>>>(W, a, ws);
  k_qproj_s1<<<dim3(BR), dim3(512), 0, stream>>>(ques, W, orig, ws);
  k_scores2<<<dim3(S / 32), dim3(512), 0, stream>>>(adj, ws);   // 5120 blocks
  k_soft_wo<<<dim3(64 + BR * 8), dim3(256), 0, stream>>>(orig, W, ws);
  k_hprime<<<dim3(BR, 4), dim3(256), 0, stream>>>(ws, out);
}